// Round 1
// baseline (210.627 us; speedup 1.0000x reference)
//
#include <hip/hip_runtime.h>
#include <stdint.h>

typedef unsigned int uint32;

#define BB 64
#define CC 256
#define OO 256
#define HH 28
#define WW 28
#define HWP 784           // 28*28
#define NWT 589824        // 256*256*9

// ---------------------------------------------------------------------------
// Kernel 1: binarize & bit-pack activations.
// apack[b][p][j] (j=0..7): bit (c%32) of word j=c/32 set iff x[b][c][p] > 0.
// Lanes = consecutive pixels p -> fully coalesced x reads.
// ---------------------------------------------------------------------------
__global__ __launch_bounds__(256) void pack_x_kernel(
    const float* __restrict__ x, uint32* __restrict__ apack) {
  int p = blockIdx.x * 256 + threadIdx.x;  // pixel 0..783 (guarded)
  int j = blockIdx.y;                      // word 0..7
  int b = blockIdx.z;
  if (p >= HWP) return;
  const float* xp = x + ((size_t)(b * CC + j * 32) * HWP) + p;
  uint32 m = 0;
#pragma unroll
  for (int cc = 0; cc < 32; ++cc) {
    float v = xp[(size_t)cc * HWP];
    m |= ((uint32)(v > 0.0f)) << cc;
  }
  apack[((size_t)b * HWP + p) * 8 + j] = m;
}

// ---------------------------------------------------------------------------
// Kernel 2: binarize & bit-pack weights.
// sign(w[n]) = sign(m[n] + sum_k rv[k]*z[k][n])  (rsqrt factor is positive).
// wpack[o][tap][j]: bit (c%32) of word j=c/32 set iff w>0.  n=(o*256+c)*9+tap.
// One wave covers 64 consecutive c for one (o,tap); __ballot builds 2 words.
// fp64 accumulation keeps us at the true sign (ref fp32 can only disagree
// for |w| ~ 1e-7, and a flip moves any output by <= 2 < threshold).
// ---------------------------------------------------------------------------
__global__ __launch_bounds__(256) void pack_w_kernel(
    const float* __restrict__ M, const float* __restrict__ Z,
    const float* __restrict__ rv, uint32* __restrict__ wpack) {
  int t = blockIdx.x * 256 + threadIdx.x;  // 0..589823
  int lane = threadIdx.x & 63;
  int idx = t >> 6;       // 0..9215
  int cblk = idx & 3;     // c block of 64
  int tap = (idx >> 2) % 9;
  int o = idx / 36;
  int c = cblk * 64 + lane;
  int n = (o * CC + c) * 9 + tap;
  double s = (double)M[n];
#pragma unroll
  for (int k = 0; k < 8; ++k)
    s += (double)rv[k] * (double)Z[(size_t)k * NWT + n];
  unsigned long long mask = __ballot(s > 0.0);
  if (lane == 0)  wpack[(o * 9 + tap) * 8 + cblk * 2]     = (uint32)mask;
  if (lane == 32) wpack[(o * 9 + tap) * 8 + cblk * 2 + 1] = (uint32)(mask >> 32);
}

// ---------------------------------------------------------------------------
// Kernel 3: binary conv + alpha scale.
// Block = (h, b); thread = o. Weights (72 u32) live in VGPRs; activation
// window addresses are wave-uniform (blockIdx + w loop) -> scalar loads,
// so the inner loop is v_xor_b32 v,s,v + v_bcnt_u32_b32 accumulate.
// dot = 256*n_valid_taps - 2*popcount_xor; out = alpha[o]*dot.
// Results staged in LDS (padded to 29 to avoid stride-28 bank conflicts)
// then written coalesced.
// ---------------------------------------------------------------------------
__global__ __launch_bounds__(256) void conv_kernel(
    const uint32* __restrict__ apack, const uint32* __restrict__ wpack,
    const float* __restrict__ alpha, float* __restrict__ out) {
  __shared__ float res[OO][WW + 1];  // +1 pad: stride 29 coprime with 32 banks

  const int h = blockIdx.x;
  const int b = blockIdx.y;
  const int o = threadIdx.x;

  // Load this thread's 9 taps x 8 words of packed weights into registers.
  uint32 wr[9][8];
  const uint4* wp = (const uint4*)(wpack + (size_t)o * 72);
#pragma unroll
  for (int t = 0; t < 9; ++t) {
    uint4 lo = wp[t * 2];
    uint4 hi = wp[t * 2 + 1];
    wr[t][0] = lo.x; wr[t][1] = lo.y; wr[t][2] = lo.z; wr[t][3] = lo.w;
    wr[t][4] = hi.x; wr[t][5] = hi.y; wr[t][6] = hi.z; wr[t][7] = hi.w;
  }
  const float av = alpha[o];

  for (int w = 0; w < WW; ++w) {
    int cnt = 0;
    int nv = 0;
#pragma unroll
    for (int dh = 0; dh < 3; ++dh) {
      int hh = h + dh - 1;
      if ((unsigned)hh >= (unsigned)HH) continue;  // uniform branch
#pragma unroll
      for (int dw = 0; dw < 3; ++dw) {
        int ww = w + dw - 1;
        if ((unsigned)ww >= (unsigned)WW) continue;  // uniform branch
        ++nv;
        const uint4* ap =
            (const uint4*)(apack + ((size_t)b * HWP + hh * WW + ww) * 8);
        uint4 a0 = ap[0];  // uniform address -> scalar load
        uint4 a1 = ap[1];
        const uint32* wt = wr[dh * 3 + dw];
        cnt += __popc(a0.x ^ wt[0]) + __popc(a0.y ^ wt[1]) +
               __popc(a0.z ^ wt[2]) + __popc(a0.w ^ wt[3]) +
               __popc(a1.x ^ wt[4]) + __popc(a1.y ^ wt[5]) +
               __popc(a1.z ^ wt[6]) + __popc(a1.w ^ wt[7]);
      }
    }
    res[o][w] = av * (float)(256 * nv - 2 * cnt);
  }
  __syncthreads();

  // Coalesced-ish write out: out[b][o][h][w], rows of 112B.
  const size_t base = (size_t)b * OO * HWP + (size_t)h * WW;
  for (int idx = threadIdx.x; idx < OO * WW; idx += 256) {
    int oo = idx / WW;
    int ww = idx - oo * WW;
    out[base + (size_t)oo * HWP + ww] = res[oo][ww];
  }
}

// ---------------------------------------------------------------------------
extern "C" void kernel_launch(void* const* d_in, const int* in_sizes, int n_in,
                              void* d_out, int out_size, void* d_ws,
                              size_t ws_size, hipStream_t stream) {
  const float* x     = (const float*)d_in[0];  // (64,256,28,28)
  const float* M     = (const float*)d_in[1];  // (256,256,3,3)
  const float* Z     = (const float*)d_in[2];  // (8,256,256,3,3)
  const float* alpha = (const float*)d_in[3];  // (256,1,1)
  const float* rv    = (const float*)d_in[4];  // (1,8)
  float* out = (float*)d_out;                  // (64,256,28,28)

  uint32* apack = (uint32*)d_ws;                        // 64*784*8 u32 = 1,605,632 B
  uint32* wpack = (uint32*)((char*)d_ws + 1605632);     // 256*9*8 u32 = 73,728 B

  // 1) pack activations
  pack_x_kernel<<<dim3(4, 8, BB), 256, 0, stream>>>(x, apack);
  // 2) pack weights
  pack_w_kernel<<<dim3(NWT / 256), 256, 0, stream>>>(M, Z, rv, wpack);
  // 3) binary conv
  conv_kernel<<<dim3(HH, BB), 256, 0, stream>>>(apack, wpack, alpha, out);
}

// Round 2
// 192.339 us; speedup vs baseline: 1.0951x; 1.0951x over previous
//
#include <hip/hip_runtime.h>
#include <stdint.h>

typedef unsigned int uint32;

#define BB 64
#define CC 256
#define OO 256
#define HH 28
#define WW 28
#define HWP 784           // 28*28
#define NWT 589824        // 256*256*9

// ---------------------------------------------------------------------------
// Kernel 1: binarize & bit-pack activations.
// apack[b][p][j] (j=0..7): bit (c%32) of word j=c/32 set iff x[b][c][p] > 0.
// Lanes = consecutive pixels p -> fully coalesced x reads.
// ---------------------------------------------------------------------------
__global__ __launch_bounds__(256) void pack_x_kernel(
    const float* __restrict__ x, uint32* __restrict__ apack) {
  int p = blockIdx.x * 256 + threadIdx.x;  // pixel 0..783 (guarded)
  int j = blockIdx.y;                      // word 0..7
  int b = blockIdx.z;
  if (p >= HWP) return;
  const float* xp = x + ((size_t)(b * CC + j * 32) * HWP) + p;
  uint32 m = 0;
#pragma unroll
  for (int cc = 0; cc < 32; ++cc) {
    float v = xp[(size_t)cc * HWP];
    m |= ((uint32)(v > 0.0f)) << cc;
  }
  apack[((size_t)b * HWP + p) * 8 + j] = m;
}

// ---------------------------------------------------------------------------
// Kernel 2 (v2): binarize & bit-pack weights, coalesced.
// Block (o, jh): handles c in [jh*64, jh*64+64) for one output channel o.
// Stage s = M + sum_k rv[k]*Z[k] into LDS with fully-coalesced reads
// (contiguous n-range per block), then bit-pack from LDS.
// LDS gather stride is 9 words — coprime with 32 banks, conflict-free.
// sign(w) = sign(m + rv.z) since the rsqrt normalizer is positive.
// ---------------------------------------------------------------------------
__global__ __launch_bounds__(256) void pack_w_kernel(
    const float* __restrict__ M, const float* __restrict__ Z,
    const float* __restrict__ rv, uint32* __restrict__ wpack) {
  __shared__ float sacc[576];
  const int o = blockIdx.x;   // 0..255
  const int jh = blockIdx.y;  // 0..3 -> words j = jh*2, jh*2+1
  const int tid = threadIdx.x;
  const size_t base = (size_t)o * 2304 + (size_t)jh * 576;

  float r[8];
#pragma unroll
  for (int k = 0; k < 8; ++k) r[k] = rv[k];

#pragma unroll
  for (int ii = 0; ii < 3; ++ii) {
    int i = tid + ii * 256;
    if (i < 576) {
      float s = M[base + i];
#pragma unroll
      for (int k = 0; k < 8; ++k) s += r[k] * Z[(size_t)k * NWT + base + i];
      sacc[i] = s;
    }
  }
  __syncthreads();

  if (tid < 18) {
    int tap = tid % 9;
    int jj = tid / 9;  // 0..1
    uint32 m = 0;
#pragma unroll
    for (int cc = 0; cc < 32; ++cc) {
      float v = sacc[(jj * 32 + cc) * 9 + tap];
      m |= ((uint32)(v > 0.0f)) << cc;
    }
    wpack[(o * 9 + tap) * 8 + jh * 2 + jj] = m;
  }
}

// ---------------------------------------------------------------------------
// Kernel 3: binary conv + alpha scale.
// Block = (h, b); thread = o. Weights (72 u32) live in VGPRs —
// __launch_bounds__(256,3) raises the VGPR cap to ~168 so they actually
// stay resident (R1: default bounds gave VGPR_Count=44 -> weight re-loads
// inside the w loop = 2.4x VALU bloat). Activation window addresses are
// wave-uniform (blockIdx + loop vars) -> scalar s_load (SGPR_Count=112 in
// R1 confirms), so the inner loop is v_xor_b32 v,s,v + v_bcnt accumulate.
// dot = 256*n_valid_taps - 2*popcount_xor; out = alpha[o]*dot.
// Results staged in padded LDS then written coalesced.
// ---------------------------------------------------------------------------
__global__ __launch_bounds__(256, 3) void conv_kernel(
    const uint32* __restrict__ apack, const uint32* __restrict__ wpack,
    const float* __restrict__ alpha, float* __restrict__ out) {
  __shared__ float res[OO][WW + 1];  // +1 pad: stride 29 coprime with 32 banks

  const int h = blockIdx.x;
  const int b = blockIdx.y;
  const int o = threadIdx.x;

  // Load this thread's 9 taps x 8 words of packed weights into registers.
  uint32 wr[9][8];
  const uint4* wp = (const uint4*)(wpack + (size_t)o * 72);
#pragma unroll
  for (int t = 0; t < 9; ++t) {
    uint4 lo = wp[t * 2];
    uint4 hi = wp[t * 2 + 1];
    wr[t][0] = lo.x; wr[t][1] = lo.y; wr[t][2] = lo.z; wr[t][3] = lo.w;
    wr[t][4] = hi.x; wr[t][5] = hi.y; wr[t][6] = hi.z; wr[t][7] = hi.w;
  }
  const float av = alpha[o];

  for (int w = 0; w < WW; ++w) {
    int cnt = 0;
    int nv = 0;
#pragma unroll
    for (int dh = 0; dh < 3; ++dh) {
      int hh = h + dh - 1;
      if ((unsigned)hh >= (unsigned)HH) continue;  // uniform branch
#pragma unroll
      for (int dw = 0; dw < 3; ++dw) {
        int ww = w + dw - 1;
        if ((unsigned)ww >= (unsigned)WW) continue;  // uniform branch
        ++nv;
        const uint4* ap =
            (const uint4*)(apack + ((size_t)b * HWP + hh * WW + ww) * 8);
        uint4 a0 = ap[0];  // uniform address -> scalar load
        uint4 a1 = ap[1];
        const uint32* wt = wr[dh * 3 + dw];
        cnt += __popc(a0.x ^ wt[0]) + __popc(a0.y ^ wt[1]) +
               __popc(a0.z ^ wt[2]) + __popc(a0.w ^ wt[3]) +
               __popc(a1.x ^ wt[4]) + __popc(a1.y ^ wt[5]) +
               __popc(a1.z ^ wt[6]) + __popc(a1.w ^ wt[7]);
      }
    }
    res[o][w] = av * (float)(256 * nv - 2 * cnt);
  }
  __syncthreads();

  // Coalesced write out: out[b][o][h][w], rows of 112B.
  const size_t base = (size_t)b * OO * HWP + (size_t)h * WW;
  for (int idx = threadIdx.x; idx < OO * WW; idx += 256) {
    int oo = idx / WW;
    int ww = idx - oo * WW;
    out[base + (size_t)oo * HWP + ww] = res[oo][ww];
  }
}

// ---------------------------------------------------------------------------
extern "C" void kernel_launch(void* const* d_in, const int* in_sizes, int n_in,
                              void* d_out, int out_size, void* d_ws,
                              size_t ws_size, hipStream_t stream) {
  const float* x     = (const float*)d_in[0];  // (64,256,28,28)
  const float* M     = (const float*)d_in[1];  // (256,256,3,3)
  const float* Z     = (const float*)d_in[2];  // (8,256,256,3,3)
  const float* alpha = (const float*)d_in[3];  // (256,1,1)
  const float* rv    = (const float*)d_in[4];  // (1,8)
  float* out = (float*)d_out;                  // (64,256,28,28)

  uint32* apack = (uint32*)d_ws;                        // 64*784*8 u32 = 1,605,632 B
  uint32* wpack = (uint32*)((char*)d_ws + 1605632);     // 256*9*8 u32 = 73,728 B

  // 1) pack activations
  pack_x_kernel<<<dim3(4, 8, BB), 256, 0, stream>>>(x, apack);
  // 2) pack weights (coalesced LDS-staged version)
  pack_w_kernel<<<dim3(256, 4), 256, 0, stream>>>(M, Z, rv, wpack);
  // 3) binary conv
  conv_kernel<<<dim3(HH, BB), 256, 0, stream>>>(apack, wpack, alpha, out);
}